// Round 9
// baseline (291.844 us; speedup 1.0000x reference)
//
#include <hip/hip_runtime.h>

#define N 4096

__device__ __forceinline__ void load_A(const float* __restrict__ Ag,
                                       float Ac[3][3], float& inv)
{
#pragma unroll
    for (int i = 0; i < 9; ++i) Ac[i / 3][i % 3] = Ag[i];
    inv = 1.0f / Ac[1][1];
    Ac[1][1] = 0.f;
}

__device__ __forceinline__ void make_w44(const float Ac[3][3], float wt[4][4])
{
#pragma unroll
    for (int a = 0; a < 4; ++a)
#pragma unroll
        for (int b = 0; b < 4; ++b) wt[a][b] = 0.f;
#pragma unroll
    for (int r = 0; r < 2; ++r)
#pragma unroll
        for (int c = 0; c < 2; ++c)
#pragma unroll
            for (int i = 0; i < 3; ++i)
#pragma unroll
                for (int j = 0; j < 3; ++j) wt[r + i][c + j] += Ac[i][j];
}

// scalar u_bc load: replicate edges, zero frame corners
__device__ __forceinline__ float ubc(const float* __restrict__ u, int gy, int gx)
{
    bool oy = (gy < 0) | (gy >= N);
    bool ox = (gx < 0) | (gx >= N);
    if (oy & ox) return 0.f;
    int cy = min(max(gy, 0), N - 1), cx = min(max(gx, 0), N - 1);
    return u[(size_t)cy * N + cx];
}

// Branch-free u_bc row segment: lane covers cols xm..xm+3 (aligned float4),
// plus L (xm-1) and R (xm+4) via clamped scalar loads.
__device__ __forceinline__ void load_row6(const float* __restrict__ u,
                                          int gy, int xm, int colL, int colR,
                                          bool cornL, bool cornR, bool yedge,
                                          float v[6])
{
    int cy = min(max(gy, 0), N - 1);
    const float* rowp = &u[(size_t)cy * N];
    float4 m = *(const float4*)&rowp[xm];
    float L = rowp[colL];
    float R = rowp[colR];
    if (yedge) {
        bool oob = (gy < 0) | (gy >= N);
        if (oob & cornL) L = 0.f;
        if (oob & cornR) R = 0.f;
    }
    v[0] = L; v[1] = m.x; v[2] = m.y; v[3] = m.z; v[4] = m.w; v[5] = R;
}

// ---- fused smooth(bc(u)) + restrict + restrict -> r2 (1024^2); runs once on u0 ----
__global__ __launch_bounds__(256) void smooth_restrict2_kernel(
    const float* __restrict__ u, const float* __restrict__ Ag,
    float* __restrict__ r2)
{
    int t = threadIdx.x, lane = t & 63, w = t >> 6;
    int bx = blockIdx.x, by = blockIdx.y;
    int x0 = 256 * bx;
    int Y0 = 16 * by + 4 * w;
    int gy0 = 2 * Y0 - 1;
    bool yedge = (gy0 < 0) | (gy0 + 9 >= N);
    float Ac[3][3], inv;
    load_A(Ag, Ac, inv);
    float wt[4][4];
    make_w44(Ac, wt);

    int xm = x0 + 4 * lane;
    int colL = max(xm - 1, 0), colR = min(xm + 4, N - 1);
    bool cornL = (xm - 1 < 0), cornR = (xm + 4 >= N);
    float v[10][6];
#pragma unroll
    for (int rr = 0; rr < 10; ++rr)
        load_row6(u, gy0 + rr, xm, colL, colR, cornL, cornR, yedge, v[rr]);

    float o0[4], o1[4];
#pragma unroll
    for (int q = 0; q < 4; ++q) {
        float a0 = 0.f, a1 = 0.f;
#pragma unroll
        for (int a = 0; a < 4; ++a) {
            const float* vv = v[2 * q + a];
#pragma unroll
            for (int b = 0; b < 4; ++b) {
                a0 += wt[a][b] * vv[b];
                a1 += wt[a][b] * vv[b + 2];
            }
        }
        o0[q] = 0.25f * a0;
        o1[q] = 0.25f * a1;
    }
    int Y2 = Y0 >> 1, X2 = 64 * bx + lane;
#pragma unroll
    for (int qp = 0; qp < 2; ++qp) {
        float val = 0.25f * (o0[2 * qp] + o1[2 * qp] + o0[2 * qp + 1] + o1[2 * qp + 1]);
        r2[(size_t)(Y2 + qp) * 1024 + X2] = val;
    }
}

// ---- one-shot restriction tree: r2 -> r3..r7 ----
__global__ __launch_bounds__(256) void multirestrict_kernel(
    const float* __restrict__ r2, float* __restrict__ r3, float* __restrict__ r4,
    float* __restrict__ r5, float* __restrict__ r6, float* __restrict__ r7)
{
    const int n2 = 1024, n3 = 512, n4 = 256, n5 = 128, n6 = 64, n7 = 32;
    int BX = blockIdx.x, BY = blockIdx.y;
    __shared__ float s3[16][17];
    __shared__ float s4[8][9];
    __shared__ float s5[4][5];
    __shared__ float s6[2][3];
    int t = threadIdx.x;
    {
        int y = t >> 4, x = t & 15;
        const float* b0 = &r2[(size_t)(BY * 32 + 2 * y) * n2 + BX * 32 + 2 * x];
        float2 a = *(const float2*)b0;
        float2 b = *(const float2*)(b0 + n2);
        float vv = 0.25f * (a.x + a.y + b.x + b.y);
        r3[(size_t)(BY * 16 + y) * n3 + BX * 16 + x] = vv;
        s3[y][x] = vv;
    }
    __syncthreads();
    if (t < 64) {
        int y = t >> 3, x = t & 7;
        float vv = 0.25f * (s3[2 * y][2 * x] + s3[2 * y][2 * x + 1] +
                            s3[2 * y + 1][2 * x] + s3[2 * y + 1][2 * x + 1]);
        r4[(size_t)(BY * 8 + y) * n4 + BX * 8 + x] = vv;
        s4[y][x] = vv;
    }
    __syncthreads();
    if (t < 16) {
        int y = t >> 2, x = t & 3;
        float vv = 0.25f * (s4[2 * y][2 * x] + s4[2 * y][2 * x + 1] +
                            s4[2 * y + 1][2 * x] + s4[2 * y + 1][2 * x + 1]);
        r5[(size_t)(BY * 4 + y) * n5 + BX * 4 + x] = vv;
        s5[y][x] = vv;
    }
    __syncthreads();
    if (t < 4) {
        int y = t >> 1, x = t & 1;
        float vv = 0.25f * (s5[2 * y][2 * x] + s5[2 * y][2 * x + 1] +
                            s5[2 * y + 1][2 * x] + s5[2 * y + 1][2 * x + 1]);
        r6[(size_t)(BY * 2 + y) * n6 + BX * 2 + x] = vv;
        s6[y][x] = vv;
    }
    __syncthreads();
    if (t == 0) {
        r7[(size_t)BY * n7 + BX] =
            0.25f * (s6[0][0] + s6[0][1] + s6[1][0] + s6[1][1]);
    }
}

// ---- fused coarse up-chain: r7..r3 -> e@512 ----
__global__ __launch_bounds__(256) void coarse_up_kernel(
    const float* __restrict__ r7, const float* __restrict__ r6,
    const float* __restrict__ r5, const float* __restrict__ r4,
    const float* __restrict__ r3, const float* __restrict__ Ag,
    float* __restrict__ e512)
{
    int bx = blockIdx.x, by = blockIdx.y;
    int t = threadIdx.x;
    __shared__ float s7[32][33];
    __shared__ float s64[64][65];
    __shared__ float s128[11][12];
    __shared__ float s256[18][19];
    float Ac[3][3], inv;
    load_A(Ag, Ac, inv);
    for (int i = t; i < 1024; i += 256) s7[i >> 5][i & 31] = r7[i] * inv;
    __syncthreads();
    for (int i = t; i < 4096; i += 256) {
        int y = i >> 6, x = i & 63;
        float ctr = s7[y >> 1][x >> 1];
        float sm = 0.f;
#pragma unroll
        for (int dy = -1; dy <= 1; ++dy)
#pragma unroll
            for (int dx = -1; dx <= 1; ++dx) {
                if (dy == 0 && dx == 0) continue;
                int yy = y + dy, xx = x + dx;
                float pe = 0.f;
                if (yy >= 0 && yy < 64 && xx >= 0 && xx < 64) pe = s7[yy >> 1][xx >> 1];
                sm += Ac[dy + 1][dx + 1] * pe;
            }
        s64[y][x] = ctr - sm * inv + r6[i] * inv;
    }
    __syncthreads();
    int R1 = 8 * by - 2, C1 = 8 * bx - 2;
    if (t < 121) {
        int pr = t / 11, pc = t % 11;
        int gy = R1 + pr, gx = C1 + pc;
        if (gy >= 0 && gy < 128 && gx >= 0 && gx < 128) {
            float ctr = s64[gy >> 1][gx >> 1];
            float sm = 0.f;
#pragma unroll
            for (int dy = -1; dy <= 1; ++dy)
#pragma unroll
                for (int dx = -1; dx <= 1; ++dx) {
                    if (dy == 0 && dx == 0) continue;
                    int yy = gy + dy, xx = gx + dx;
                    float pe = 0.f;
                    if (yy >= 0 && yy < 128 && xx >= 0 && xx < 128) pe = s64[yy >> 1][xx >> 1];
                    sm += Ac[dy + 1][dx + 1] * pe;
                }
            s128[pr][pc] = ctr - sm * inv + r5[(size_t)gy * 128 + gx] * inv;
        }
    }
    __syncthreads();
    int R2l = 16 * by - 1, C2l = 16 * bx - 1;
    for (int i = t; i < 324; i += 256) {
        int pr = i / 18, pc = i % 18;
        int gy = R2l + pr, gx = C2l + pc;
        if (gy >= 0 && gy < 256 && gx >= 0 && gx < 256) {
            float ctr = s128[(gy >> 1) - R1][(gx >> 1) - C1];
            float sm = 0.f;
#pragma unroll
            for (int dy = -1; dy <= 1; ++dy)
#pragma unroll
                for (int dx = -1; dx <= 1; ++dx) {
                    if (dy == 0 && dx == 0) continue;
                    int yy = gy + dy, xx = gx + dx;
                    float pe = 0.f;
                    if (yy >= 0 && yy < 256 && xx >= 0 && xx < 256)
                        pe = s128[(yy >> 1) - R1][(xx >> 1) - C1];
                    sm += Ac[dy + 1][dx + 1] * pe;
                }
            s256[pr][pc] = ctr - sm * inv + r4[(size_t)gy * 256 + gx] * inv;
        }
    }
    __syncthreads();
#pragma unroll
    for (int k = 0; k < 4; ++k) {
        int idx = t + 256 * k;
        int y = 32 * by + (idx >> 5), x = 32 * bx + (idx & 31);
        float ctr = s256[(y >> 1) - R2l][(x >> 1) - C2l];
        float sm = 0.f;
#pragma unroll
        for (int dy = -1; dy <= 1; ++dy)
#pragma unroll
            for (int dx = -1; dx <= 1; ++dx) {
                if (dy == 0 && dx == 0) continue;
                int yy = y + dy, xx = x + dx;
                float pe = 0.f;
                if (yy >= 0 && yy < 512 && xx >= 0 && xx < 512)
                    pe = s256[(yy >> 1) - R2l][(xx >> 1) - C2l];
                sm += Ac[dy + 1][dx + 1] * pe;
            }
        e512[(size_t)y * 512 + x] = ctr - sm * inv + r3[(size_t)y * 512 + x] * inv;
    }
}

// ---- fused: e512 -> e1024 -> e2048(regs) -> u update; MODE 0: also r2_next; MODE 1: minmax ----
// Block: 256 thr = 4 waves; u tile 256 cols x 32 rows. Grid (16,128).
template <int MODE>
__global__ __launch_bounds__(256) void final_fused_kernel(
    const float* __restrict__ u, const float* __restrict__ e512,
    const float* __restrict__ r2in, float* __restrict__ r2out,
    const float* __restrict__ Ag, float* __restrict__ uo,
    float* __restrict__ partials)
{
    const int n = N;
    int t = threadIdx.x, lane = t & 63, w = t >> 6;
    int bx = blockIdx.x, by = blockIdx.y;
    int x0 = 256 * bx, y0 = 32 * by;
    __shared__ float s512v[6][36];
    __shared__ float s1024[10][68];
    __shared__ float su[34][261];   // u_next_bc: rows y0-1..y0+32, cols x0-1..x0+256
    __shared__ float sW6[36];
    float Ac[3][3], inv;
    load_A(Ag, Ac, inv);
    float wt[4][4];
    make_w44(Ac, wt);

    // issue u row loads early for MLP
    int yb = y0 + 8 * w;
    int gy0 = yb - 1;
    bool yedge = (gy0 < 0) | (gy0 + 9 >= n);
    int xm = x0 + 4 * lane;
    int colL = max(xm - 1, 0), colR = min(xm + 4, n - 1);
    bool cornL = (xm - 1 < 0), cornR = (xm + 4 >= n);
    float v[10][6];
#pragma unroll
    for (int rr = 0; rr < 10; ++rr)
        load_row6(u, gy0 + rr, xm, colL, colR, cornL, cornR, yedge, v[rr]);

    int S5r = 4 * by - 1, S5c = 32 * bx - 1;
    if (t < 216) {
        int pr = t / 36, pc = t - (t / 36) * 36;
        int gy = S5r + pr, gx = S5c + pc;
        float vv = 0.f;
        if (pc < 34 && gy >= 0 && gy < 512 && gx >= 0 && gx < 512)
            vv = e512[(size_t)gy * 512 + gx];
        s512v[pr][pc] = vv;
    }
    if (MODE == 0 && t < 36) {  // W6 = restrict(2x2) of w44 pair: 6x6 combined kernel
        int a = t / 6, b = t % 6;
        float s = 0.f;
#pragma unroll
        for (int p = 0; p < 2; ++p)
#pragma unroll
            for (int q = 0; q < 2; ++q) {
                int i = a - 2 * p, j = b - 2 * q;
                if (i >= 0 && i < 4 && j >= 0 && j < 4) s += wt[i][j];
            }
        sW6[t] = s;
    }
    __syncthreads();
    // e1024 patch 10x66 (oob entries = 0)
    int R10 = 8 * by - 1, C10 = 64 * bx - 1;
    for (int i = t; i < 680; i += 256) {
        int pr = i / 68, pc = i - (i / 68) * 68;
        if (pc < 66) {
            int gy = R10 + pr, gx = C10 + pc;
            float val = 0.f;
            if (gy >= 0 && gy < 1024 && gx >= 0 && gx < 1024) {
                float ctr = s512v[(gy >> 1) - S5r][(gx >> 1) - S5c];
                float sm = 0.f;
#pragma unroll
                for (int dy = -1; dy <= 1; ++dy)
#pragma unroll
                    for (int dx = -1; dx <= 1; ++dx) {
                        if (dy == 0 && dx == 0) continue;
                        sm += Ac[dy + 1][dx + 1] *
                              s512v[((gy + dy) >> 1) - S5r][((gx + dx) >> 1) - S5c];
                    }
                val = ctr - sm * inv + r2in[(size_t)gy * 1024 + gx] * inv;
            }
            s1024[pr][pc] = val;
        }
    }
    __syncthreads();
    // per-thread e2048: 4 rows x 2 cols; r1 recomputed in regs from v[][]
    float e2[4][2];
    int EY0 = 16 * by + 4 * w, EX0 = 128 * bx + 2 * lane;
#pragma unroll
    for (int a = 0; a < 4; ++a) {
        int gy = EY0 + a;
        float a0 = 0.f, a1 = 0.f;
#pragma unroll
        for (int i = 0; i < 4; ++i) {
            const float* vv = v[2 * a + i];
#pragma unroll
            for (int j = 0; j < 4; ++j) {
                a0 += wt[i][j] * vv[j];
                a1 += wt[i][j] * vv[j + 2];
            }
        }
        float r1v[2] = {0.25f * a0, 0.25f * a1};
#pragma unroll
        for (int b = 0; b < 2; ++b) {
            int gx = EX0 + b;
            float ctr = s1024[(gy >> 1) - R10][(gx >> 1) - C10];
            float sm = 0.f;
#pragma unroll
            for (int dy = -1; dy <= 1; ++dy)
#pragma unroll
                for (int dx = -1; dx <= 1; ++dx) {
                    if (dy == 0 && dx == 0) continue;
                    sm += Ac[dy + 1][dx + 1] *
                          s1024[((gy + dy) >> 1) - R10][((gx + dx) >> 1) - C10];
                }
            e2[a][b] = ctr - sm * inv + r1v[b] * inv;
        }
    }
    // u update: 8 rows
    float mn = 3.402823466e+38f, mx = -3.402823466e+38f;
#pragma unroll
    for (int r = 0; r < 8; ++r) {
        int y = yb + r;
        const float* va = v[r];
        const float* vb = v[r + 1];
        const float* vc = v[r + 2];
        float out[4];
#pragma unroll
        for (int c = 0; c < 4; ++c) {
            float sm = Ac[0][0] * va[c] + Ac[0][1] * va[c + 1] + Ac[0][2] * va[c + 2]
                     + Ac[1][0] * vb[c]                        + Ac[1][2] * vb[c + 2]
                     + Ac[2][0] * vc[c] + Ac[2][1] * vc[c + 1] + Ac[2][2] * vc[c + 2];
            out[c] = vb[c + 1] - e2[r >> 1][c >> 1] - sm * inv;
        }
        *(float4*)&uo[(size_t)y * n + xm] =
            make_float4(out[0], out[1], out[2], out[3]);
        if (MODE == 1) {
            mn = fminf(mn, fminf(fminf(out[0], out[1]), fminf(out[2], out[3])));
            mx = fmaxf(mx, fmaxf(fmaxf(out[0], out[1]), fmaxf(out[2], out[3])));
        } else {
            int lr = 1 + 8 * w + r, lc = 1 + 4 * lane;
#pragma unroll
            for (int c = 0; c < 4; ++c) su[lr][lc + c] = out[c];
        }
    }

    if (MODE == 0) {
        __syncthreads();
        // halo ring of u_next_bc (580 cells)
        for (int i = t; i < 580; i += 256) {
            int gy, gx;
            if (i < 258)      { gy = y0 - 1;          gx = x0 - 1 + i; }
            else if (i < 516) { gy = y0 + 32;         gx = x0 - 1 + (i - 258); }
            else if (i < 548) { gy = y0 + (i - 516);  gx = x0 - 1; }
            else              { gy = y0 + (i - 548);  gx = x0 + 256; }
            float val;
            bool oy = (gy < 0) | (gy >= n), ox = (gx < 0) | (gx >= n);
            if (oy & ox) {
                val = 0.f;  // frame corner
            } else {
                int cy = min(max(gy, 0), n - 1), cx = min(max(gx, 0), n - 1);
                bool inblk = (cy >= y0) & (cy < y0 + 32) & (cx >= x0) & (cx < x0 + 256);
                if ((oy | ox) && inblk) {
                    val = su[cy - (y0 - 1)][cx - (x0 - 1)];  // replicate-bc
                } else {
                    // full recompute of u_next at in-domain (cy,cx)
                    float sm = 0.f;
#pragma unroll
                    for (int ii = 0; ii < 3; ++ii)
#pragma unroll
                        for (int jj = 0; jj < 3; ++jj)
                            sm += Ac[ii][jj] * ubc(u, cy - 1 + ii, cx - 1 + jj);
                    int Y = cy >> 1, X = cx >> 1;
                    float r1v = 0.f;
#pragma unroll
                    for (int ii = 0; ii < 4; ++ii)
#pragma unroll
                        for (int jj = 0; jj < 4; ++jj)
                            r1v += wt[ii][jj] * ubc(u, 2 * Y - 1 + ii, 2 * X - 1 + jj);
                    r1v *= 0.25f;
                    float ctr = s1024[(Y >> 1) - R10][(X >> 1) - C10];
                    float sme = 0.f;
#pragma unroll
                    for (int dy = -1; dy <= 1; ++dy)
#pragma unroll
                        for (int dx = -1; dx <= 1; ++dx) {
                            if (dy == 0 && dx == 0) continue;
                            sme += Ac[dy + 1][dx + 1] *
                                   s1024[((Y + dy) >> 1) - R10][((X + dx) >> 1) - C10];
                        }
                    float e2v = ctr - sme * inv + r1v * inv;
                    val = u[(size_t)cy * n + cx] - e2v - sm * inv;
                }
            }
            su[gy - (y0 - 1)][gx - (x0 - 1)] = val;
        }
        __syncthreads();
        // r2_next: 8x64 cells per block, 2 per thread, via 6x6 W6 over su
#pragma unroll
        for (int cc = 0; cc < 2; ++cc) {
            int c = t + 256 * cc;
            int iy = c & 7, ix = c >> 3;
            float acc = 0.f;
#pragma unroll
            for (int a = 0; a < 6; ++a)
#pragma unroll
                for (int b = 0; b < 6; ++b)
                    acc += sW6[6 * a + b] * su[4 * iy + a][4 * ix + b];
            r2out[(size_t)(8 * by + iy) * 1024 + 64 * bx + ix] = 0.0625f * acc;
        }
    }

    if (MODE == 1) {
#pragma unroll
        for (int off = 32; off > 0; off >>= 1) {
            mn = fminf(mn, __shfl_down(mn, off));
            mx = fmaxf(mx, __shfl_down(mx, off));
        }
        __shared__ float smn[4], smx[4];
        if (lane == 0) { smn[w] = mn; smx[w] = mx; }
        __syncthreads();
        if (t == 0) {
            mn = smn[0]; mx = smx[0];
            for (int wq = 1; wq < 4; ++wq) { mn = fminf(mn, smn[wq]); mx = fmaxf(mx, smx[wq]); }
            int bid = by * 16 + bx;
            partials[2 * bid] = mn;
            partials[2 * bid + 1] = mx;
        }
    }
}

__global__ __launch_bounds__(1024) void minmax_final_kernel(
    const float* __restrict__ partials, float* __restrict__ mm)
{
    float mn = 3.402823466e+38f, mx = -3.402823466e+38f;
    for (int i = threadIdx.x; i < 2048; i += 1024) {
        mn = fminf(mn, partials[2 * i]);
        mx = fmaxf(mx, partials[2 * i + 1]);
    }
#pragma unroll
    for (int off = 32; off > 0; off >>= 1) {
        mn = fminf(mn, __shfl_down(mn, off));
        mx = fmaxf(mx, __shfl_down(mx, off));
    }
    __shared__ float smn[16], smx[16];
    int lane = threadIdx.x & 63, wv = threadIdx.x >> 6;
    if (lane == 0) { smn[wv] = mn; smx[wv] = mx; }
    __syncthreads();
    if (threadIdx.x == 0) {
        mn = smn[0]; mx = smx[0];
        for (int w = 1; w < 16; ++w) { mn = fminf(mn, smn[w]); mx = fmaxf(mx, smx[w]); }
        mm[0] = mn;
        mm[1] = mx;
    }
}

__global__ __launch_bounds__(256) void normalize_kernel(
    float* __restrict__ u, const float* __restrict__ mm)
{
    size_t i = ((size_t)blockIdx.x * 256 + threadIdx.x) * 4;
    float mn = mm[0];
    float sc = 1.0f / (mm[1] - mm[0]);
    float4 v = *(float4*)&u[i];
    v.x = (v.x - mn) * sc;
    v.y = (v.y - mn) * sc;
    v.z = (v.z - mn) * sc;
    v.w = (v.w - mn) * sc;
    *(float4*)&u[i] = v;
}

extern "C" void kernel_launch(void* const* d_in, const int* in_sizes, int n_in,
                              void* d_out, int out_size, void* d_ws, size_t ws_size,
                              hipStream_t stream)
{
    const float* A  = (const float*)d_in[0];
    const float* u0 = (const float*)d_in[1];
    float* uout = (float*)d_out;
    float* ws = (float*)d_ws;

    size_t off = 0;
    float* r2A = ws + off; off += 1024ull * 1024;
    float* r2B = ws + off; off += 1024ull * 1024;
    float* r3 = ws + off; off += 512ull * 512;
    float* r4 = ws + off; off += 256ull * 256;
    float* r5 = ws + off; off += 128ull * 128;
    float* r6 = ws + off; off += 64ull * 64;
    float* r7 = ws + off; off += 32ull * 32;
    float* e5 = ws + off; off += 512ull * 512;
    float* uA = ws + off; off += 4096ull * 4096;
    float* partials = ws + off; off += 4096;
    float* mm = ws + off; off += 2;

    dim3 blk(256);
    // r2 for iteration 0 comes from u0 via the standalone smooth; afterwards
    // final_fused<0> of iteration it produces r2 for iteration it+1 (ping-pong).
    smooth_restrict2_kernel<<<dim3(16, 128), blk, 0, stream>>>(u0, A, r2A);
    float* r2cur = r2A;
    float* r2nxt = r2B;
    for (int it = 0; it < 4; ++it) {
        const float* us = (it == 0) ? u0 : ((it == 2) ? uout : uA);
        float* dst = (it & 1) ? uout : uA;
        multirestrict_kernel<<<dim3(32, 32), blk, 0, stream>>>(r2cur, r3, r4, r5, r6, r7);
        coarse_up_kernel<<<dim3(16, 16), blk, 0, stream>>>(r7, r6, r5, r4, r3, A, e5);
        if (it == 3)
            final_fused_kernel<1><<<dim3(16, 128), blk, 0, stream>>>(
                us, e5, r2cur, r2nxt, A, dst, partials);
        else
            final_fused_kernel<0><<<dim3(16, 128), blk, 0, stream>>>(
                us, e5, r2cur, r2nxt, A, dst, partials);
        float* tmp = r2cur; r2cur = r2nxt; r2nxt = tmp;
    }
    minmax_final_kernel<<<1, 1024, 0, stream>>>(partials, mm);
    normalize_kernel<<<16384, 256, 0, stream>>>(uout, mm);
}